// Round 10
// baseline (143.307 us; speedup 1.0000x reference)
//
#include <hip/hip_runtime.h>
#include <hip/hip_bf16.h>

#define B_    4
#define N_    16384
#define D_    128
#define P_    100
#define BN_   65536      // B_*N_
#define PBN_  6553600    // P_*BN_
#define PPAD  112        // P padded to 7*16 MFMA p-tiles (k_proj)
#define KPAD  128        // P padded to 128 for k_comb's K dimension
#define NBIN  4096

typedef __attribute__((ext_vector_type(8))) short short8;   // 8 bf16 = 4 VGPR
typedef __attribute__((ext_vector_type(4))) float floatx4;  // MFMA C/D

// bf16 <-> f32 via raw bits (RNE; inputs are finite)
__device__ __forceinline__ unsigned short f2b(float f) {
    unsigned u = __float_as_uint(f);
    return (unsigned short)((u + 0x7FFFu + ((u >> 16) & 1u)) >> 16);
}
__device__ __forceinline__ float b2f(unsigned short h) {
    return __uint_as_float(((unsigned)h) << 16);
}

// ---------------------------------------------------------------------------
// Kernel 1 (was k_norm+k_proj): projections via bf16 MFMA 16x16x32 with
// IN-BLOCK theta normalization (R10).  th is 51 KB L2-resident; each block
// redundantly computes the 100 row norms (2 threads/row: 16 float4 sums +
// one shfl_xor) and scales during th_s staging — deletes the k_norm kernel
// and one launch/drain boundary.  Blocks 0..127 also write one thbT row each
// for k_comb (coalesced; ready long before k_comb launches).
// R8-proven body: [64][72] shared buf, 4 store phases, ay[7] in VGPRs.
// LDS 40,192 B -> still 4 blocks/CU, 1.0 rounds.
// ---------------------------------------------------------------------------
__global__ __launch_bounds__(256, 4) void k_proj(
    const float* __restrict__ x, const float* __restrict__ y,
    const float* __restrict__ th, unsigned short* __restrict__ thbT,
    unsigned short* __restrict__ xp, unsigned short* __restrict__ yp) {
    __shared__ unsigned short th_s[15232];    // [112][136] 30,464 B
    __shared__ unsigned short buf[4608];      // [64][72]    9,216 B
    __shared__ float invn[128];               //               512 B
    const int tid  = threadIdx.x;
    const int w    = tid >> 6;                // wave 0..3 -> rows w*16..+15
    const int lane = tid & 63;
    const int n    = lane & 15;
    const int quad = lane >> 4;
    const int row0 = blockIdx.x * 64;

    // ---- issue this lane's x/y B-fragment loads FIRST (hide under norms) ----
    const float* xr = x + (size_t)(row0 + w * 16 + n) * D_ + quad * 8;
    const float* yr = y + (size_t)(row0 + w * 16 + n) * D_ + quad * 8;
    float4 lx[8], ly[8];
    #pragma unroll
    for (int ks = 0; ks < 4; ++ks) {
        lx[2*ks]   = *(const float4*)(xr + ks * 32);
        lx[2*ks+1] = *(const float4*)(xr + ks * 32 + 4);
        ly[2*ks]   = *(const float4*)(yr + ks * 32);
        ly[2*ks+1] = *(const float4*)(yr + ks * 32 + 4);
    }

    // ---- in-block theta norms: 2 threads per row p = tid>>1 ----
    {
        int p = tid >> 1, half = tid & 1;
        float s = 0.f;
        if (p < P_) {
            const float* tr = th + (size_t)p * D_ + half * 64;
            #pragma unroll
            for (int i = 0; i < 16; ++i) {
                float4 v = *(const float4*)(tr + i * 4);
                s += v.x * v.x + v.y * v.y + v.z * v.z + v.w * v.w;
            }
        }
        s += __shfl_xor(s, 1, 64);            // pair (2p, 2p+1) same wave
        if (half == 0 && p < 128)
            invn[p] = (p < P_) ? 1.f / fmaxf(sqrtf(s), 1e-12f) : 0.f;
    }
    __syncthreads();                          // invn ready

    // ---- stage th_s = bf16(th * invn), rows >=100 zero ----
    for (int g = tid; g < 1792; g += 256) {   // 112 rows x 16 col-chunks
        int r = g >> 4, c = (g & 15) << 3;
        ushort4 lo, hi;
        if (r < P_) {
            float sc = invn[r];
            float4 a = *(const float4*)(th + (size_t)r * D_ + c);
            float4 b = *(const float4*)(th + (size_t)r * D_ + c + 4);
            lo = make_ushort4(f2b(a.x * sc), f2b(a.y * sc), f2b(a.z * sc), f2b(a.w * sc));
            hi = make_ushort4(f2b(b.x * sc), f2b(b.y * sc), f2b(b.z * sc), f2b(b.w * sc));
        } else {
            lo = make_ushort4(0, 0, 0, 0);
            hi = make_ushort4(0, 0, 0, 0);
        }
        *(ushort4*)(th_s + r * 136 + c)     = lo;
        *(ushort4*)(th_s + r * 136 + c + 4) = hi;
    }
    __syncthreads();                          // th_s staged

    // ---- blocks 0..127: write thbT row d = blockIdx.x for k_comb ----
    if (blockIdx.x < KPAD && tid < KPAD) {
        int d = blockIdx.x;
        unsigned short v = (tid < PPAD) ? th_s[tid * 136 + d] : (unsigned short)0;
        thbT[(size_t)d * KPAD + tid] = v;
    }

    // ---- convert x/y fragments in-register ----
    short8 bx[4], by[4];
    #pragma unroll
    for (int ks = 0; ks < 4; ++ks) {
        short8 tx, ty;
        tx[0] = (short)f2b(lx[2*ks].x);   ty[0] = (short)f2b(ly[2*ks].x);
        tx[1] = (short)f2b(lx[2*ks].y);   ty[1] = (short)f2b(ly[2*ks].y);
        tx[2] = (short)f2b(lx[2*ks].z);   ty[2] = (short)f2b(ly[2*ks].z);
        tx[3] = (short)f2b(lx[2*ks].w);   ty[3] = (short)f2b(ly[2*ks].w);
        tx[4] = (short)f2b(lx[2*ks+1].x); ty[4] = (short)f2b(ly[2*ks+1].x);
        tx[5] = (short)f2b(lx[2*ks+1].y); ty[5] = (short)f2b(ly[2*ks+1].y);
        tx[6] = (short)f2b(lx[2*ks+1].z); ty[6] = (short)f2b(ly[2*ks+1].z);
        tx[7] = (short)f2b(lx[2*ks+1].w); ty[7] = (short)f2b(ly[2*ks+1].w);
        bx[ks] = tx; by[ks] = ty;
    }

    floatx4 ay[7];                            // held y accumulators (28 VGPR)

    // ---- phase A: x projections p 0..63 ----
    #pragma unroll
    for (int pt = 0; pt < 4; ++pt) {
        floatx4 accx = {0.f, 0.f, 0.f, 0.f};
        floatx4 accy = {0.f, 0.f, 0.f, 0.f};
        #pragma unroll
        for (int ks = 0; ks < 4; ++ks) {
            short8 a = *(const short8*)(th_s + (pt * 16 + n) * 136 + ks * 32 + quad * 8);
            accx = __builtin_amdgcn_mfma_f32_16x16x32_bf16(a, bx[ks], accx, 0, 0, 0);
            accy = __builtin_amdgcn_mfma_f32_16x16x32_bf16(a, by[ks], accy, 0, 0, 0);
        }
        #pragma unroll
        for (int reg = 0; reg < 4; ++reg)
            buf[(pt * 16 + quad * 4 + reg) * 72 + w * 16 + n] = f2b(accx[reg]);
        ay[pt] = accy;
    }
    __syncthreads();
    for (int g = tid; g < 512; g += 256) {
        int p = g >> 3, c = (g & 7) << 3;
        *(uint4*)(xp + (size_t)p * BN_ + row0 + c) = *(const uint4*)(buf + p * 72 + c);
    }
    __syncthreads();

    // ---- phase B: x projections p 64..99 ----
    #pragma unroll
    for (int pt = 4; pt < 7; ++pt) {
        floatx4 accx = {0.f, 0.f, 0.f, 0.f};
        floatx4 accy = {0.f, 0.f, 0.f, 0.f};
        #pragma unroll
        for (int ks = 0; ks < 4; ++ks) {
            short8 a = *(const short8*)(th_s + (pt * 16 + n) * 136 + ks * 32 + quad * 8);
            accx = __builtin_amdgcn_mfma_f32_16x16x32_bf16(a, bx[ks], accx, 0, 0, 0);
            accy = __builtin_amdgcn_mfma_f32_16x16x32_bf16(a, by[ks], accy, 0, 0, 0);
        }
        #pragma unroll
        for (int reg = 0; reg < 4; ++reg)
            buf[((pt - 4) * 16 + quad * 4 + reg) * 72 + w * 16 + n] = f2b(accx[reg]);
        ay[pt] = accy;
    }
    __syncthreads();
    for (int g = tid; g < 288; g += 256) {    // p 64..99 (36 rows)
        int p = g >> 3, c = (g & 7) << 3;
        *(uint4*)(xp + (size_t)(64 + p) * BN_ + row0 + c) = *(const uint4*)(buf + p * 72 + c);
    }
    __syncthreads();

    // ---- phase C: y projections p 0..63 ----
    #pragma unroll
    for (int pt = 0; pt < 4; ++pt)
        #pragma unroll
        for (int reg = 0; reg < 4; ++reg)
            buf[(pt * 16 + quad * 4 + reg) * 72 + w * 16 + n] = f2b(ay[pt][reg]);
    __syncthreads();
    for (int g = tid; g < 512; g += 256) {
        int p = g >> 3, c = (g & 7) << 3;
        *(uint4*)(yp + (size_t)p * BN_ + row0 + c) = *(const uint4*)(buf + p * 72 + c);
    }
    __syncthreads();

    // ---- phase D: y projections p 64..99 ----
    #pragma unroll
    for (int pt = 4; pt < 7; ++pt)
        #pragma unroll
        for (int reg = 0; reg < 4; ++reg)
            buf[((pt - 4) * 16 + quad * 4 + reg) * 72 + w * 16 + n] = f2b(ay[pt][reg]);
    __syncthreads();
    for (int g = tid; g < 288; g += 256) {
        int p = g >> 3, c = (g & 7) << 3;
        *(uint4*)(yp + (size_t)(64 + p) * BN_ + row0 + c) = *(const uint4*)(buf + p * 72 + c);
    }
}

// ---------------------------------------------------------------------------
// Kernel 2: fused counting sort + rank + diff.  (R9-proven one-round
// variant: packed hist y lo16 / x hi16; stream-count keeping only atomic
// returns; L2 reload for scatter/gather; launch_bounds(1024,8) -> VGPR<=64,
// 2 blocks/CU, 400 blocks = one round.)  UNCHANGED.
// ---------------------------------------------------------------------------
__device__ __forceinline__ int binof(float v) {
    int k = (int)((v + 8.0f) * 256.0f);
    return k < 0 ? 0 : (k > NBIN - 1 ? NBIN - 1 : k);
}

__device__ __forceinline__ void scan4(unsigned* hist, volatile unsigned* wsum, int t) {
    unsigned v[4], run = 0;
    #pragma unroll
    for (int i = 0; i < 4; ++i) { unsigned h = hist[t * 4 + i]; v[i] = run; run += h; }
    const int lane = t & 63, w = t >> 6;
    unsigned inc = run;
    #pragma unroll
    for (int off = 1; off < 64; off <<= 1) {
        unsigned nbr = __shfl_up(inc, off, 64);
        if (lane >= off) inc += nbr;
    }
    if (lane == 63) wsum[w] = inc;
    __syncthreads();
    if (t == 0) {
        unsigned r2 = 0;
        #pragma unroll
        for (int i = 0; i < 16; ++i) { unsigned h = wsum[i]; wsum[i] = r2; r2 += h; }
    }
    __syncthreads();
    unsigned base = wsum[w] + (inc - run);
    #pragma unroll
    for (int i = 0; i < 4; ++i) hist[t * 4 + i] = base + v[i];
}

__global__ __launch_bounds__(1024, 8) void k_sortdiff(
    const unsigned short* __restrict__ xp, const unsigned short* __restrict__ yp,
    unsigned short* __restrict__ diff) {
    __shared__ unsigned hist[NBIN];           // 16 KB (packed y|x)
    __shared__ unsigned short ysort[N_];      // 32 KB
    __shared__ unsigned wsum[16];
    const int t = threadIdx.x;
    const unsigned* ypd = (const unsigned*)(yp + (size_t)blockIdx.x * N_);
    const unsigned* xpd = (const unsigned*)(xp + (size_t)blockIdx.x * N_);
    unsigned*       dfd = (unsigned*)(diff + (size_t)blockIdx.x * N_);

    #pragma unroll
    for (int i = 0; i < 4; ++i) hist[t + i * 1024] = 0;
    __syncthreads();

    // ---- packed count pass: stream loads, keep ONLY atomic returns ----
    unsigned jy[8], jx[8];
    #pragma unroll
    for (int i = 0; i < 2; ++i) {
        uint4 a = *(const uint4*)(ypd + i * 4096 + t * 4);
        unsigned aws[4] = {a.x, a.y, a.z, a.w};
        #pragma unroll
        for (int q = 0; q < 4; ++q) {
            unsigned j0 = atomicAdd(&hist[binof(b2f((unsigned short)(aws[q] & 0xffff)))], 1u);
            unsigned j1 = atomicAdd(&hist[binof(b2f((unsigned short)(aws[q] >> 16)))], 1u);
            jy[4*i + q] = (j0 & 0xffffu) | (j1 << 16);
        }
    }
    #pragma unroll
    for (int i = 0; i < 2; ++i) {
        uint4 c = *(const uint4*)(xpd + i * 4096 + t * 4);
        unsigned cws[4] = {c.x, c.y, c.z, c.w};
        #pragma unroll
        for (int q = 0; q < 4; ++q) {
            unsigned i0 = atomicAdd(&hist[binof(b2f((unsigned short)(cws[q] & 0xffff)))], 0x10000u);
            unsigned i1 = atomicAdd(&hist[binof(b2f((unsigned short)(cws[q] >> 16)))], 0x10000u);
            jx[4*i + q] = (i0 >> 16) | (i1 & 0xffff0000u);
        }
    }
    __syncthreads();
    scan4(hist, wsum, t);                     // packed exclusive prefix, both fields
    __syncthreads();

    // ---- scatter y into LDS (reload y from L2, recompute bins) ----
    #pragma unroll
    for (int i = 0; i < 2; ++i) {
        uint4 a = *(const uint4*)(ypd + i * 4096 + t * 4);
        unsigned aws[4] = {a.x, a.y, a.z, a.w};
        #pragma unroll
        for (int q = 0; q < 4; ++q) {
            int k = 4*i + q;
            unsigned short e0 = (unsigned short)(aws[q] & 0xffff);
            unsigned short e1 = (unsigned short)(aws[q] >> 16);
            ysort[(hist[binof(b2f(e0))] & 0xffffu) + (jy[k] & 0xffffu)] = e0;
            ysort[(hist[binof(b2f(e1))] & 0xffffu) + (jy[k] >> 16)]     = e1;
        }
    }
    __syncthreads();

    // ---- gather transported y + diff (reload x from L2) ----
    #pragma unroll
    for (int i = 0; i < 2; ++i) {
        uint4 c = *(const uint4*)(xpd + i * 4096 + t * 4);
        unsigned cws[4] = {c.x, c.y, c.z, c.w};
        unsigned o[4];
        #pragma unroll
        for (int q = 0; q < 4; ++q) {
            int k = 4*i + q;
            float x0 = b2f((unsigned short)(cws[q] & 0xffff));
            float x1 = b2f((unsigned short)(cws[q] >> 16));
            unsigned r0 = (hist[binof(x0)] >> 16) + (jx[k] & 0xffffu);
            unsigned r1 = (hist[binof(x1)] >> 16) + (jx[k] >> 16);
            unsigned short d0 = f2b(b2f(ysort[r0]) - x0);
            unsigned short d1 = f2b(b2f(ysort[r1]) - x1);
            o[q] = (unsigned)d0 | ((unsigned)d1 << 16);
        }
        *(uint4*)(dfd + i * 4096 + t * 4) = make_uint4(o[0], o[1], o[2], o[3]);
    }
}

// ---------------------------------------------------------------------------
// Kernel 3: combine via bf16 MFMA, transpose fused into the LDS stage.
// (R8-proven exact-occupancy version: thbT staged in two halves, LDS 34.8 KB
// -> 4 blocks/CU, 1.0 rounds.)  UNCHANGED.
// ---------------------------------------------------------------------------
__global__ __launch_bounds__(256, 4) void k_comb(
    const float* __restrict__ x, const unsigned short* __restrict__ diff,
    const unsigned short* __restrict__ thbT, float* __restrict__ out) {
    __shared__ unsigned short ths[64 * 136];  // 17,408 B (half of thbT)
    __shared__ unsigned Lp[64 * 68];          // 17,408 B  [k2][row] pair-packed
    const int tid  = threadIdx.x;
    const int w    = tid >> 6;                // wave -> rows w*16..+15
    const int lane = tid & 63;
    const int n16  = lane & 15;
    const int quad = lane >> 4;
    const int row0 = blockIdx.x * 64;

    for (int g = tid; g < 1024; g += 256) {   // thbT rows 0..63 -> LDS
        int r = g >> 4, c = (g & 15) << 3;
        *(uint4*)(ths + r * 136 + c) = *(const uint4*)(thbT + r * KPAD + c);
    }
    for (int g = tid; g < 952; g += 256) Lp[50 * 68 + g] = 0;   // k2=50..63 pad
    for (int g = tid; g < 400; g += 256) {    // 50 p-pairs x 8 row-groups
        int p2 = g >> 3, rg = (g & 7) << 3;
        uint4 a = *(const uint4*)(diff + (size_t)(2 * p2) * BN_ + row0 + rg);
        uint4 b = *(const uint4*)(diff + (size_t)(2 * p2 + 1) * BN_ + row0 + rg);
        unsigned* dst = Lp + p2 * 68 + rg;
        dst[0] = (a.x & 0xffffu) | (b.x << 16);
        dst[1] = (a.x >> 16)     | (b.x & 0xffff0000u);
        dst[2] = (a.y & 0xffffu) | (b.y << 16);
        dst[3] = (a.y >> 16)     | (b.y & 0xffff0000u);
        dst[4] = (a.z & 0xffffu) | (b.z << 16);
        dst[5] = (a.z >> 16)     | (b.z & 0xffff0000u);
        dst[6] = (a.w & 0xffffu) | (b.w << 16);
        dst[7] = (a.w >> 16)     | (b.w & 0xffff0000u);
    }
    __syncthreads();

    // A-frags: lane row r = w*16+n16, k = ks*32 + quad*8 + 0..7 (held both passes)
    const int r = w * 16 + n16;
    short8 af[4];
    #pragma unroll
    for (int ks = 0; ks < 4; ++ks) {
        union { unsigned u[4]; short8 v; } tu;
        #pragma unroll
        for (int m = 0; m < 4; ++m)
            tu.u[m] = Lp[(ks * 16 + quad * 4 + m) * 68 + r];
        af[ks] = tu.v;
    }

    const float invP = 1.0f / (float)P_;
    const size_t rbase = (size_t)(row0 + w * 16 + quad * 4) * D_ + n16;

    // ---- pass 0: d 0..63 ----
    #pragma unroll
    for (int nt = 0; nt < 4; ++nt) {
        floatx4 acc = {0.f, 0.f, 0.f, 0.f};
        #pragma unroll
        for (int ks = 0; ks < 4; ++ks) {
            short8 b = *(const short8*)(ths + (nt * 16 + n16) * 136 + ks * 32 + quad * 8);
            acc = __builtin_amdgcn_mfma_f32_16x16x32_bf16(af[ks], b, acc, 0, 0, 0);
        }
        #pragma unroll
        for (int reg = 0; reg < 4; ++reg) {
            size_t o = rbase + (size_t)reg * D_ + nt * 16;
            out[o] = fmaf(acc[reg], invP, x[o]);
        }
    }
    __syncthreads();                          // all waves done with ths half0

    for (int g = tid; g < 1024; g += 256) {   // thbT rows 64..127 -> LDS
        int r2 = g >> 4, c = (g & 15) << 3;
        *(uint4*)(ths + r2 * 136 + c) = *(const uint4*)(thbT + (size_t)(64 + r2) * KPAD + c);
    }
    __syncthreads();

    // ---- pass 1: d 64..127 ----
    #pragma unroll
    for (int nt = 0; nt < 4; ++nt) {
        floatx4 acc = {0.f, 0.f, 0.f, 0.f};
        #pragma unroll
        for (int ks = 0; ks < 4; ++ks) {
            short8 b = *(const short8*)(ths + (nt * 16 + n16) * 136 + ks * 32 + quad * 8);
            acc = __builtin_amdgcn_mfma_f32_16x16x32_bf16(af[ks], b, acc, 0, 0, 0);
        }
        #pragma unroll
        for (int reg = 0; reg < 4; ++reg) {
            size_t o = rbase + (size_t)reg * D_ + (64 + nt * 16);
            out[o] = fmaf(acc[reg], invP, x[o]);
        }
    }
}

// ---------------------------------------------------------------------------
// Workspace (bytes): thbT[32KB, 64KB) xp[64KB, +13.1MB) yp(+13.1MB)
// => ~26.3 MB. diff overwrites xp in place.  (thb slot retired — k_norm
// fused into k_proj; thbT written by k_proj blocks 0..127.)
// ---------------------------------------------------------------------------
extern "C" void kernel_launch(void* const* d_in, const int* in_sizes, int n_in,
                              void* d_out, int out_size, void* d_ws, size_t ws_size,
                              hipStream_t stream) {
    const float* x  = (const float*)d_in[0];
    const float* y  = (const float*)d_in[1];
    const float* th = (const float*)d_in[2];
    float* out = (float*)d_out;
    char*  wsb = (char*)d_ws;

    unsigned short* thbT = (unsigned short*)(wsb + 32768);
    unsigned short* xpb  = (unsigned short*)(wsb + 65536);
    unsigned short* ypb  = xpb + PBN_;

    k_proj<<<BN_ / 64, 256, 0, stream>>>(x, y, th, thbT, xpb, ypb);
    k_sortdiff<<<P_ * B_, 1024, 0, stream>>>(xpb, ypb, xpb);
    k_comb<<<BN_ / 64, 256, 0, stream>>>(x, xpb, thbT, out);
}

// Round 11
// 139.266 us; speedup vs baseline: 1.0290x; 1.0290x over previous
//
#include <hip/hip_runtime.h>
#include <hip/hip_bf16.h>

#define B_    4
#define N_    16384
#define D_    128
#define P_    100
#define BN_   65536      // B_*N_
#define PBN_  6553600    // P_*BN_
#define PPAD  112        // P padded to 7*16 MFMA p-tiles (k_proj)
#define KPAD  128        // P padded to 128 for k_comb's K dimension
#define NBIN  4096

typedef __attribute__((ext_vector_type(8))) short short8;   // 8 bf16 = 4 VGPR
typedef __attribute__((ext_vector_type(4))) float floatx4;  // MFMA C/D

// bf16 <-> f32 via raw bits (RNE; inputs are finite)
__device__ __forceinline__ unsigned short f2b(float f) {
    unsigned u = __float_as_uint(f);
    return (unsigned short)((u + 0x7FFFu + ((u >> 16) & 1u)) >> 16);
}
__device__ __forceinline__ float b2f(unsigned short h) {
    return __uint_as_float(((unsigned)h) << 16);
}

// ---------------------------------------------------------------------------
// Kernel 1: theta normalization -> thb[p][d] (k_proj A-operand, rows >=100
// zero) and thbT[d][p] (k_comb B-operand, cols >=100 zero; NaN-safe K-pad).
// R10 post-mortem: fusing this into k_proj multiplied theta reads x1024
// blocks (+8 us) to save ~3 — separate kernel is the right structure.
// ---------------------------------------------------------------------------
__global__ void k_norm(const float* __restrict__ th,
                       unsigned short* __restrict__ thb,
                       unsigned short* __restrict__ thbT) {
    int p = blockIdx.x;       // 0..127
    int d = threadIdx.x;      // 0..127
    float v = 0.f;
    if (p < P_) v = th[p * D_ + d];
    float s = v * v;
    #pragma unroll
    for (int o = 32; o > 0; o >>= 1) s += __shfl_down(s, o, 64);
    __shared__ float red[2];
    if ((d & 63) == 0) red[d >> 6] = s;
    __syncthreads();
    float norm = fmaxf(sqrtf(red[0] + red[1]), 1e-12f);
    unsigned short r = f2b(v / norm);       // p>=100 -> 0/1e-12 = +0
    if (p < PPAD) thb[p * D_ + d] = r;
    thbT[d * KPAD + p] = r;
}

// ---------------------------------------------------------------------------
// Kernel 2: projections via bf16 MFMA 16x16x32.  (R8/R9-proven exact-
// occupancy version: [64][72] shared buf, 4 store phases, ay[7] in VGPRs,
// LDS 39.7 KB -> 4 blocks/CU, 1.0 rounds.)  UNCHANGED.
// ---------------------------------------------------------------------------
__global__ __launch_bounds__(256, 4) void k_proj(
    const float* __restrict__ x, const float* __restrict__ y,
    const unsigned short* __restrict__ thb,
    unsigned short* __restrict__ xp, unsigned short* __restrict__ yp) {
    __shared__ unsigned short th_s[15232];    // [112][136] 30,464 B
    __shared__ unsigned short buf[4608];      // [64][72]    9,216 B
    const int tid  = threadIdx.x;
    const int w    = tid >> 6;                // wave 0..3 -> rows w*16..+15
    const int lane = tid & 63;
    const int n    = lane & 15;
    const int quad = lane >> 4;
    const int row0 = blockIdx.x * 64;

    for (int g = tid; g < 1792; g += 256) {   // theta 112x128 bf16 -> LDS
        int r = g >> 4, c = (g & 15) << 3;
        *(uint4*)(th_s + r * 136 + c) = *(const uint4*)(thb + r * D_ + c);
    }

    // direct global loads of this lane's B-fragments, convert in-register
    const float* xr = x + (size_t)(row0 + w * 16 + n) * D_ + quad * 8;
    const float* yr = y + (size_t)(row0 + w * 16 + n) * D_ + quad * 8;
    short8 bx[4], by[4];
    {
        float4 lx[8];
        #pragma unroll
        for (int ks = 0; ks < 4; ++ks) {
            lx[2*ks]   = *(const float4*)(xr + ks * 32);
            lx[2*ks+1] = *(const float4*)(xr + ks * 32 + 4);
        }
        #pragma unroll
        for (int ks = 0; ks < 4; ++ks) {
            short8 t;
            t[0] = (short)f2b(lx[2*ks].x);   t[1] = (short)f2b(lx[2*ks].y);
            t[2] = (short)f2b(lx[2*ks].z);   t[3] = (short)f2b(lx[2*ks].w);
            t[4] = (short)f2b(lx[2*ks+1].x); t[5] = (short)f2b(lx[2*ks+1].y);
            t[6] = (short)f2b(lx[2*ks+1].z); t[7] = (short)f2b(lx[2*ks+1].w);
            bx[ks] = t;
        }
    }
    {
        float4 ly[8];
        #pragma unroll
        for (int ks = 0; ks < 4; ++ks) {
            ly[2*ks]   = *(const float4*)(yr + ks * 32);
            ly[2*ks+1] = *(const float4*)(yr + ks * 32 + 4);
        }
        #pragma unroll
        for (int ks = 0; ks < 4; ++ks) {
            short8 t;
            t[0] = (short)f2b(ly[2*ks].x);   t[1] = (short)f2b(ly[2*ks].y);
            t[2] = (short)f2b(ly[2*ks].z);   t[3] = (short)f2b(ly[2*ks].w);
            t[4] = (short)f2b(ly[2*ks+1].x); t[5] = (short)f2b(ly[2*ks+1].y);
            t[6] = (short)f2b(ly[2*ks+1].z); t[7] = (short)f2b(ly[2*ks+1].w);
            by[ks] = t;
        }
    }
    __syncthreads();                          // theta staged

    floatx4 ay[7];                            // held y accumulators (28 VGPR)

    // ---- phase A: x projections p 0..63 ----
    #pragma unroll
    for (int pt = 0; pt < 4; ++pt) {
        floatx4 accx = {0.f, 0.f, 0.f, 0.f};
        floatx4 accy = {0.f, 0.f, 0.f, 0.f};
        #pragma unroll
        for (int ks = 0; ks < 4; ++ks) {
            short8 a = *(const short8*)(th_s + (pt * 16 + n) * 136 + ks * 32 + quad * 8);
            accx = __builtin_amdgcn_mfma_f32_16x16x32_bf16(a, bx[ks], accx, 0, 0, 0);
            accy = __builtin_amdgcn_mfma_f32_16x16x32_bf16(a, by[ks], accy, 0, 0, 0);
        }
        #pragma unroll
        for (int reg = 0; reg < 4; ++reg)
            buf[(pt * 16 + quad * 4 + reg) * 72 + w * 16 + n] = f2b(accx[reg]);
        ay[pt] = accy;
    }
    __syncthreads();
    for (int g = tid; g < 512; g += 256) {
        int p = g >> 3, c = (g & 7) << 3;
        *(uint4*)(xp + (size_t)p * BN_ + row0 + c) = *(const uint4*)(buf + p * 72 + c);
    }
    __syncthreads();

    // ---- phase B: x projections p 64..99 ----
    #pragma unroll
    for (int pt = 4; pt < 7; ++pt) {
        floatx4 accx = {0.f, 0.f, 0.f, 0.f};
        floatx4 accy = {0.f, 0.f, 0.f, 0.f};
        #pragma unroll
        for (int ks = 0; ks < 4; ++ks) {
            short8 a = *(const short8*)(th_s + (pt * 16 + n) * 136 + ks * 32 + quad * 8);
            accx = __builtin_amdgcn_mfma_f32_16x16x32_bf16(a, bx[ks], accx, 0, 0, 0);
            accy = __builtin_amdgcn_mfma_f32_16x16x32_bf16(a, by[ks], accy, 0, 0, 0);
        }
        #pragma unroll
        for (int reg = 0; reg < 4; ++reg)
            buf[((pt - 4) * 16 + quad * 4 + reg) * 72 + w * 16 + n] = f2b(accx[reg]);
        ay[pt] = accy;
    }
    __syncthreads();
    for (int g = tid; g < 288; g += 256) {    // p 64..99 (36 rows)
        int p = g >> 3, c = (g & 7) << 3;
        *(uint4*)(xp + (size_t)(64 + p) * BN_ + row0 + c) = *(const uint4*)(buf + p * 72 + c);
    }
    __syncthreads();

    // ---- phase C: y projections p 0..63 ----
    #pragma unroll
    for (int pt = 0; pt < 4; ++pt)
        #pragma unroll
        for (int reg = 0; reg < 4; ++reg)
            buf[(pt * 16 + quad * 4 + reg) * 72 + w * 16 + n] = f2b(ay[pt][reg]);
    __syncthreads();
    for (int g = tid; g < 512; g += 256) {
        int p = g >> 3, c = (g & 7) << 3;
        *(uint4*)(yp + (size_t)p * BN_ + row0 + c) = *(const uint4*)(buf + p * 72 + c);
    }
    __syncthreads();

    // ---- phase D: y projections p 64..99 ----
    #pragma unroll
    for (int pt = 4; pt < 7; ++pt)
        #pragma unroll
        for (int reg = 0; reg < 4; ++reg)
            buf[((pt - 4) * 16 + quad * 4 + reg) * 72 + w * 16 + n] = f2b(ay[pt][reg]);
    __syncthreads();
    for (int g = tid; g < 288; g += 256) {
        int p = g >> 3, c = (g & 7) << 3;
        *(uint4*)(yp + (size_t)(64 + p) * BN_ + row0 + c) = *(const uint4*)(buf + p * 72 + c);
    }
}

// ---------------------------------------------------------------------------
// Kernel 3: fused counting sort + rank + diff.  (R9-proven one-round
// variant: packed hist y lo16 / x hi16; stream-count keeping only atomic
// returns; L2 reload for scatter/gather; launch_bounds(1024,8) -> VGPR<=64,
// 2 blocks/CU, 400 blocks = one round.)  UNCHANGED.
// ---------------------------------------------------------------------------
__device__ __forceinline__ int binof(float v) {
    int k = (int)((v + 8.0f) * 256.0f);
    return k < 0 ? 0 : (k > NBIN - 1 ? NBIN - 1 : k);
}

__device__ __forceinline__ void scan4(unsigned* hist, volatile unsigned* wsum, int t) {
    unsigned v[4], run = 0;
    #pragma unroll
    for (int i = 0; i < 4; ++i) { unsigned h = hist[t * 4 + i]; v[i] = run; run += h; }
    const int lane = t & 63, w = t >> 6;
    unsigned inc = run;
    #pragma unroll
    for (int off = 1; off < 64; off <<= 1) {
        unsigned nbr = __shfl_up(inc, off, 64);
        if (lane >= off) inc += nbr;
    }
    if (lane == 63) wsum[w] = inc;
    __syncthreads();
    if (t == 0) {
        unsigned r2 = 0;
        #pragma unroll
        for (int i = 0; i < 16; ++i) { unsigned h = wsum[i]; wsum[i] = r2; r2 += h; }
    }
    __syncthreads();
    unsigned base = wsum[w] + (inc - run);
    #pragma unroll
    for (int i = 0; i < 4; ++i) hist[t * 4 + i] = base + v[i];
}

__global__ __launch_bounds__(1024, 8) void k_sortdiff(
    const unsigned short* __restrict__ xp, const unsigned short* __restrict__ yp,
    unsigned short* __restrict__ diff) {
    __shared__ unsigned hist[NBIN];           // 16 KB (packed y|x)
    __shared__ unsigned short ysort[N_];      // 32 KB
    __shared__ unsigned wsum[16];
    const int t = threadIdx.x;
    const unsigned* ypd = (const unsigned*)(yp + (size_t)blockIdx.x * N_);
    const unsigned* xpd = (const unsigned*)(xp + (size_t)blockIdx.x * N_);
    unsigned*       dfd = (unsigned*)(diff + (size_t)blockIdx.x * N_);

    #pragma unroll
    for (int i = 0; i < 4; ++i) hist[t + i * 1024] = 0;
    __syncthreads();

    // ---- packed count pass: stream loads, keep ONLY atomic returns ----
    unsigned jy[8], jx[8];
    #pragma unroll
    for (int i = 0; i < 2; ++i) {
        uint4 a = *(const uint4*)(ypd + i * 4096 + t * 4);
        unsigned aws[4] = {a.x, a.y, a.z, a.w};
        #pragma unroll
        for (int q = 0; q < 4; ++q) {
            unsigned j0 = atomicAdd(&hist[binof(b2f((unsigned short)(aws[q] & 0xffff)))], 1u);
            unsigned j1 = atomicAdd(&hist[binof(b2f((unsigned short)(aws[q] >> 16)))], 1u);
            jy[4*i + q] = (j0 & 0xffffu) | (j1 << 16);
        }
    }
    #pragma unroll
    for (int i = 0; i < 2; ++i) {
        uint4 c = *(const uint4*)(xpd + i * 4096 + t * 4);
        unsigned cws[4] = {c.x, c.y, c.z, c.w};
        #pragma unroll
        for (int q = 0; q < 4; ++q) {
            unsigned i0 = atomicAdd(&hist[binof(b2f((unsigned short)(cws[q] & 0xffff)))], 0x10000u);
            unsigned i1 = atomicAdd(&hist[binof(b2f((unsigned short)(cws[q] >> 16)))], 0x10000u);
            jx[4*i + q] = (i0 >> 16) | (i1 & 0xffff0000u);
        }
    }
    __syncthreads();
    scan4(hist, wsum, t);                     // packed exclusive prefix, both fields
    __syncthreads();

    // ---- scatter y into LDS (reload y from L2, recompute bins) ----
    #pragma unroll
    for (int i = 0; i < 2; ++i) {
        uint4 a = *(const uint4*)(ypd + i * 4096 + t * 4);
        unsigned aws[4] = {a.x, a.y, a.z, a.w};
        #pragma unroll
        for (int q = 0; q < 4; ++q) {
            int k = 4*i + q;
            unsigned short e0 = (unsigned short)(aws[q] & 0xffff);
            unsigned short e1 = (unsigned short)(aws[q] >> 16);
            ysort[(hist[binof(b2f(e0))] & 0xffffu) + (jy[k] & 0xffffu)] = e0;
            ysort[(hist[binof(b2f(e1))] & 0xffffu) + (jy[k] >> 16)]     = e1;
        }
    }
    __syncthreads();

    // ---- gather transported y + diff (reload x from L2) ----
    #pragma unroll
    for (int i = 0; i < 2; ++i) {
        uint4 c = *(const uint4*)(xpd + i * 4096 + t * 4);
        unsigned cws[4] = {c.x, c.y, c.z, c.w};
        unsigned o[4];
        #pragma unroll
        for (int q = 0; q < 4; ++q) {
            int k = 4*i + q;
            float x0 = b2f((unsigned short)(cws[q] & 0xffff));
            float x1 = b2f((unsigned short)(cws[q] >> 16));
            unsigned r0 = (hist[binof(x0)] >> 16) + (jx[k] & 0xffffu);
            unsigned r1 = (hist[binof(x1)] >> 16) + (jx[k] >> 16);
            unsigned short d0 = f2b(b2f(ysort[r0]) - x0);
            unsigned short d1 = f2b(b2f(ysort[r1]) - x1);
            o[q] = (unsigned)d0 | ((unsigned)d1 << 16);
        }
        *(uint4*)(dfd + i * 4096 + t * 4) = make_uint4(o[0], o[1], o[2], o[3]);
    }
}

// ---------------------------------------------------------------------------
// Kernel 4: combine via bf16 MFMA, transpose fused into the LDS stage.
// R11: VECTORIZED EPILOGUE.  The old epilogue did 64 scalar-dword global
// ops/thread (32 x-loads + 32 out-stores, 4x64B segments per wave-instr).
// Now: hold acc across both MFMA passes (+32 VGPR), then stage the 64x128
// f32 C-tile into LDS (reusing dead ths+Lp space; stride 132 floats ->
// acc-writes 2-way bank-aliased = free, reads 16B-aligned) and run a
// cooperative epilogue: per wave-instr 256 consecutive floats (float4
// x-load + fma + float4 out-store = 1 KB/instr).  LDS 34,816 B unchanged
// -> 4 blocks/CU.  Live ~110 VGPR < cap 128 of launch_bounds(256,4).
// ---------------------------------------------------------------------------
__global__ __launch_bounds__(256, 4) void k_comb(
    const float* __restrict__ x, const unsigned short* __restrict__ diff,
    const unsigned short* __restrict__ thbT, float* __restrict__ out) {
    __shared__ __align__(16) char smem[34816];
    unsigned short* ths = (unsigned short*)smem;          // [64][136] 17,408 B
    unsigned*       Lp  = (unsigned*)(smem + 17408);      // [64][68]  17,408 B
    float*          fb  = (float*)smem;                   // [64][132] 33,792 B (phase 2)
    const int tid  = threadIdx.x;
    const int w    = tid >> 6;                // wave -> rows w*16..+15
    const int lane = tid & 63;
    const int n16  = lane & 15;
    const int quad = lane >> 4;
    const int row0 = blockIdx.x * 64;

    for (int g = tid; g < 1024; g += 256) {   // thbT rows 0..63 -> LDS
        int r = g >> 4, c = (g & 15) << 3;
        *(uint4*)(ths + r * 136 + c) = *(const uint4*)(thbT + r * KPAD + c);
    }
    for (int g = tid; g < 952; g += 256) Lp[50 * 68 + g] = 0;   // k2=50..63 pad
    for (int g = tid; g < 400; g += 256) {    // 50 p-pairs x 8 row-groups
        int p2 = g >> 3, rg = (g & 7) << 3;
        uint4 a = *(const uint4*)(diff + (size_t)(2 * p2) * BN_ + row0 + rg);
        uint4 b = *(const uint4*)(diff + (size_t)(2 * p2 + 1) * BN_ + row0 + rg);
        unsigned* dst = Lp + p2 * 68 + rg;
        dst[0] = (a.x & 0xffffu) | (b.x << 16);
        dst[1] = (a.x >> 16)     | (b.x & 0xffff0000u);
        dst[2] = (a.y & 0xffffu) | (b.y << 16);
        dst[3] = (a.y >> 16)     | (b.y & 0xffff0000u);
        dst[4] = (a.z & 0xffffu) | (b.z << 16);
        dst[5] = (a.z >> 16)     | (b.z & 0xffff0000u);
        dst[6] = (a.w & 0xffffu) | (b.w << 16);
        dst[7] = (a.w >> 16)     | (b.w & 0xffff0000u);
    }
    __syncthreads();

    // A-frags: lane row r = w*16+n16, k = ks*32 + quad*8 + 0..7 (held both passes)
    const int r = w * 16 + n16;
    short8 af[4];
    #pragma unroll
    for (int ks = 0; ks < 4; ++ks) {
        union { unsigned u[4]; short8 v; } tu;
        #pragma unroll
        for (int m = 0; m < 4; ++m)
            tu.u[m] = Lp[(ks * 16 + quad * 4 + m) * 68 + r];
        af[ks] = tu.v;
    }

    // ---- pass 0 MFMA: d 0..63 (acc held) ----
    floatx4 acc0[4], acc1[4];
    #pragma unroll
    for (int nt = 0; nt < 4; ++nt) {
        floatx4 acc = {0.f, 0.f, 0.f, 0.f};
        #pragma unroll
        for (int ks = 0; ks < 4; ++ks) {
            short8 b = *(const short8*)(ths + (nt * 16 + n16) * 136 + ks * 32 + quad * 8);
            acc = __builtin_amdgcn_mfma_f32_16x16x32_bf16(af[ks], b, acc, 0, 0, 0);
        }
        acc0[nt] = acc;
    }
    __syncthreads();                          // all waves done with ths half0

    for (int g = tid; g < 1024; g += 256) {   // thbT rows 64..127 -> LDS
        int r2 = g >> 4, c = (g & 15) << 3;
        *(uint4*)(ths + r2 * 136 + c) = *(const uint4*)(thbT + (size_t)(64 + r2) * KPAD + c);
    }
    __syncthreads();

    // ---- pass 1 MFMA: d 64..127 (acc held) ----
    #pragma unroll
    for (int nt = 0; nt < 4; ++nt) {
        floatx4 acc = {0.f, 0.f, 0.f, 0.f};
        #pragma unroll
        for (int ks = 0; ks < 4; ++ks) {
            short8 b = *(const short8*)(ths + (nt * 16 + n16) * 136 + ks * 32 + quad * 8);
            acc = __builtin_amdgcn_mfma_f32_16x16x32_bf16(af[ks], b, acc, 0, 0, 0);
        }
        acc1[nt] = acc;
    }
    __syncthreads();                          // ths/Lp dead -> fb alias safe

    // ---- stage C-tile into LDS (stride 132: writes 2-way = free) ----
    {
        const int rw = w * 16 + quad * 4;     // + reg
        #pragma unroll
        for (int nt = 0; nt < 4; ++nt)
            #pragma unroll
            for (int reg = 0; reg < 4; ++reg) {
                fb[(rw + reg) * 132 + n16 + nt * 16]      = acc0[nt][reg];
                fb[(rw + reg) * 132 + n16 + nt * 16 + 64] = acc1[nt][reg];
            }
    }
    __syncthreads();

    // ---- vectorized epilogue: 8 x (1KB/wave float4 load+fma+store) ----
    const float invP = 1.0f / (float)P_;
    #pragma unroll
    for (int s = 0; s < 8; ++s) {
        int e   = s * 1024 + tid * 4;         // flat index in 64x128 tile
        int rr  = e >> 7, cc = e & 127;
        float4 f = *(const float4*)(fb + rr * 132 + cc);
        size_t o = (size_t)(row0 + rr) * D_ + cc;
        float4 xv = *(const float4*)(x + o);
        float4 ov;
        ov.x = fmaf(f.x, invP, xv.x);
        ov.y = fmaf(f.y, invP, xv.y);
        ov.z = fmaf(f.z, invP, xv.z);
        ov.w = fmaf(f.w, invP, xv.w);
        *(float4*)(out + o) = ov;
    }
}

// ---------------------------------------------------------------------------
// Workspace (bytes): thb[0, 32KB) thbT[32KB, 64KB) xp[64KB, +13.1MB)
// yp(+13.1MB) => ~26.3 MB. diff overwrites xp in place.
// ---------------------------------------------------------------------------
extern "C" void kernel_launch(void* const* d_in, const int* in_sizes, int n_in,
                              void* d_out, int out_size, void* d_ws, size_t ws_size,
                              hipStream_t stream) {
    const float* x  = (const float*)d_in[0];
    const float* y  = (const float*)d_in[1];
    const float* th = (const float*)d_in[2];
    float* out = (float*)d_out;
    char*  wsb = (char*)d_ws;

    unsigned short* thb  = (unsigned short*)wsb;
    unsigned short* thbT = (unsigned short*)(wsb + 32768);
    unsigned short* xpb  = (unsigned short*)(wsb + 65536);
    unsigned short* ypb  = xpb + PBN_;

    k_norm<<<128, 128, 0, stream>>>(th, thb, thbT);
    k_proj<<<BN_ / 64, 256, 0, stream>>>(x, y, thb, xpb, ypb);
    k_sortdiff<<<P_ * B_, 1024, 0, stream>>>(xpb, ypb, xpb);
    k_comb<<<BN_ / 64, 256, 0, stream>>>(x, xpb, thbT, out);
}

// Round 12
// 137.567 us; speedup vs baseline: 1.0417x; 1.0123x over previous
//
#include <hip/hip_runtime.h>
#include <hip/hip_bf16.h>

#define B_    4
#define N_    16384
#define D_    128
#define P_    100
#define BN_   65536      // B_*N_
#define PBN_  6553600    // P_*BN_
#define PPAD  112        // P padded to 7*16 MFMA p-tiles (k_proj)
#define KPAD  128        // P padded to 128 for k_comb's K dimension
#define NBIN  4096

typedef __attribute__((ext_vector_type(8))) short short8;   // 8 bf16 = 4 VGPR
typedef __attribute__((ext_vector_type(4))) float floatx4;  // MFMA C/D

// bf16 <-> f32 via raw bits (RNE; inputs are finite)
__device__ __forceinline__ unsigned short f2b(float f) {
    unsigned u = __float_as_uint(f);
    return (unsigned short)((u + 0x7FFFu + ((u >> 16) & 1u)) >> 16);
}
__device__ __forceinline__ float b2f(unsigned short h) {
    return __uint_as_float(((unsigned)h) << 16);
}

// ---------------------------------------------------------------------------
// Kernel 1: theta normalization -> thb[p][d] (k_proj A-operand, rows >=100
// zero) and thbT[d][p] (k_comb B-operand, cols >=100 zero; NaN-safe K-pad).
// ---------------------------------------------------------------------------
__global__ void k_norm(const float* __restrict__ th,
                       unsigned short* __restrict__ thb,
                       unsigned short* __restrict__ thbT) {
    int p = blockIdx.x;       // 0..127
    int d = threadIdx.x;      // 0..127
    float v = 0.f;
    if (p < P_) v = th[p * D_ + d];
    float s = v * v;
    #pragma unroll
    for (int o = 32; o > 0; o >>= 1) s += __shfl_down(s, o, 64);
    __shared__ float red[2];
    if ((d & 63) == 0) red[d >> 6] = s;
    __syncthreads();
    float norm = fmaxf(sqrtf(red[0] + red[1]), 1e-12f);
    unsigned short r = f2b(v / norm);       // p>=100 -> 0/1e-12 = +0
    if (p < PPAD) thb[p * D_ + d] = r;
    thbT[d * KPAD + p] = r;
}

// ---------------------------------------------------------------------------
// Kernel 2: projections via bf16 MFMA 16x16x32.
// R12: 256-ROW TILE.  Same proven per-thread body as R8/R9 (bx/by frags,
// ay[7] held, 4 store phases), re-gridded to 1024 threads (16 waves, w=0..15)
// x 256 rows/block, grid 256 = 1 block/CU x 256 CU = exactly one round.
// Theta staged ONCE per 256 rows (staging traffic / 4).  Uses the only
// empirically-safe high-thread launch-bounds config (1024,4): cap 128 VGPR,
// live ~100, no spill (R2/R4/R9 evidence; (512,4) and (1024,8) both spill).
// LDS 64,256 B -> 1 block/CU, 16 waves/CU (same waves as R8's 4x4).
// ---------------------------------------------------------------------------
__global__ __launch_bounds__(1024, 4) void k_proj(
    const float* __restrict__ x, const float* __restrict__ y,
    const unsigned short* __restrict__ thb,
    unsigned short* __restrict__ xp, unsigned short* __restrict__ yp) {
    __shared__ unsigned short th_s[15232];    // [112][136] 30,464 B
    __shared__ unsigned short buf[16896];     // [64][264]  33,792 B
    const int tid  = threadIdx.x;             // 0..1023
    const int w    = tid >> 6;                // wave 0..15 -> rows w*16..+15
    const int lane = tid & 63;
    const int n    = lane & 15;
    const int quad = lane >> 4;
    const int row0 = blockIdx.x * 256;

    for (int g = tid; g < 1792; g += 1024) {  // theta 112x128 bf16 -> LDS
        int r = g >> 4, c = (g & 15) << 3;
        *(uint4*)(th_s + r * 136 + c) = *(const uint4*)(thb + r * D_ + c);
    }

    // direct global loads of this lane's B-fragments, convert in-register
    const float* xr = x + (size_t)(row0 + w * 16 + n) * D_ + quad * 8;
    const float* yr = y + (size_t)(row0 + w * 16 + n) * D_ + quad * 8;
    short8 bx[4], by[4];
    {
        float4 lx[8];
        #pragma unroll
        for (int ks = 0; ks < 4; ++ks) {
            lx[2*ks]   = *(const float4*)(xr + ks * 32);
            lx[2*ks+1] = *(const float4*)(xr + ks * 32 + 4);
        }
        #pragma unroll
        for (int ks = 0; ks < 4; ++ks) {
            short8 t;
            t[0] = (short)f2b(lx[2*ks].x);   t[1] = (short)f2b(lx[2*ks].y);
            t[2] = (short)f2b(lx[2*ks].z);   t[3] = (short)f2b(lx[2*ks].w);
            t[4] = (short)f2b(lx[2*ks+1].x); t[5] = (short)f2b(lx[2*ks+1].y);
            t[6] = (short)f2b(lx[2*ks+1].z); t[7] = (short)f2b(lx[2*ks+1].w);
            bx[ks] = t;
        }
    }
    {
        float4 ly[8];
        #pragma unroll
        for (int ks = 0; ks < 4; ++ks) {
            ly[2*ks]   = *(const float4*)(yr + ks * 32);
            ly[2*ks+1] = *(const float4*)(yr + ks * 32 + 4);
        }
        #pragma unroll
        for (int ks = 0; ks < 4; ++ks) {
            short8 t;
            t[0] = (short)f2b(ly[2*ks].x);   t[1] = (short)f2b(ly[2*ks].y);
            t[2] = (short)f2b(ly[2*ks].z);   t[3] = (short)f2b(ly[2*ks].w);
            t[4] = (short)f2b(ly[2*ks+1].x); t[5] = (short)f2b(ly[2*ks+1].y);
            t[6] = (short)f2b(ly[2*ks+1].z); t[7] = (short)f2b(ly[2*ks+1].w);
            by[ks] = t;
        }
    }
    __syncthreads();                          // theta staged

    floatx4 ay[7];                            // held y accumulators (28 VGPR)

    // ---- phase A: x projections p 0..63 ----
    #pragma unroll
    for (int pt = 0; pt < 4; ++pt) {
        floatx4 accx = {0.f, 0.f, 0.f, 0.f};
        floatx4 accy = {0.f, 0.f, 0.f, 0.f};
        #pragma unroll
        for (int ks = 0; ks < 4; ++ks) {
            short8 a = *(const short8*)(th_s + (pt * 16 + n) * 136 + ks * 32 + quad * 8);
            accx = __builtin_amdgcn_mfma_f32_16x16x32_bf16(a, bx[ks], accx, 0, 0, 0);
            accy = __builtin_amdgcn_mfma_f32_16x16x32_bf16(a, by[ks], accy, 0, 0, 0);
        }
        #pragma unroll
        for (int reg = 0; reg < 4; ++reg)
            buf[(pt * 16 + quad * 4 + reg) * 264 + w * 16 + n] = f2b(accx[reg]);
        ay[pt] = accy;
    }
    __syncthreads();
    for (int g = tid; g < 2048; g += 1024) {  // x p 0..63, 256 cols
        int p = g >> 5, c = (g & 31) << 3;
        *(uint4*)(xp + (size_t)p * BN_ + row0 + c) = *(const uint4*)(buf + p * 264 + c);
    }
    __syncthreads();

    // ---- phase B: x projections p 64..99 ----
    #pragma unroll
    for (int pt = 4; pt < 7; ++pt) {
        floatx4 accx = {0.f, 0.f, 0.f, 0.f};
        floatx4 accy = {0.f, 0.f, 0.f, 0.f};
        #pragma unroll
        for (int ks = 0; ks < 4; ++ks) {
            short8 a = *(const short8*)(th_s + (pt * 16 + n) * 136 + ks * 32 + quad * 8);
            accx = __builtin_amdgcn_mfma_f32_16x16x32_bf16(a, bx[ks], accx, 0, 0, 0);
            accy = __builtin_amdgcn_mfma_f32_16x16x32_bf16(a, by[ks], accy, 0, 0, 0);
        }
        #pragma unroll
        for (int reg = 0; reg < 4; ++reg)
            buf[((pt - 4) * 16 + quad * 4 + reg) * 264 + w * 16 + n] = f2b(accx[reg]);
        ay[pt] = accy;
    }
    __syncthreads();
    for (int g = tid; g < 1152; g += 1024) {  // p 64..99 (36 rows)
        int p = g >> 5, c = (g & 31) << 3;
        *(uint4*)(xp + (size_t)(64 + p) * BN_ + row0 + c) = *(const uint4*)(buf + p * 264 + c);
    }
    __syncthreads();

    // ---- phase C: y projections p 0..63 ----
    #pragma unroll
    for (int pt = 0; pt < 4; ++pt)
        #pragma unroll
        for (int reg = 0; reg < 4; ++reg)
            buf[(pt * 16 + quad * 4 + reg) * 264 + w * 16 + n] = f2b(ay[pt][reg]);
    __syncthreads();
    for (int g = tid; g < 2048; g += 1024) {
        int p = g >> 5, c = (g & 31) << 3;
        *(uint4*)(yp + (size_t)p * BN_ + row0 + c) = *(const uint4*)(buf + p * 264 + c);
    }
    __syncthreads();

    // ---- phase D: y projections p 64..99 ----
    #pragma unroll
    for (int pt = 4; pt < 7; ++pt)
        #pragma unroll
        for (int reg = 0; reg < 4; ++reg)
            buf[((pt - 4) * 16 + quad * 4 + reg) * 264 + w * 16 + n] = f2b(ay[pt][reg]);
    __syncthreads();
    for (int g = tid; g < 1152; g += 1024) {
        int p = g >> 5, c = (g & 31) << 3;
        *(uint4*)(yp + (size_t)(64 + p) * BN_ + row0 + c) = *(const uint4*)(buf + p * 264 + c);
    }
}

// ---------------------------------------------------------------------------
// Kernel 3: fused counting sort + rank + diff.  (R9-proven one-round
// variant: packed hist y lo16 / x hi16; stream-count keeping only atomic
// returns; L2 reload for scatter/gather; launch_bounds(1024,8) -> VGPR<=64,
// 2 blocks/CU, 400 blocks = one round.)  UNCHANGED.
// ---------------------------------------------------------------------------
__device__ __forceinline__ int binof(float v) {
    int k = (int)((v + 8.0f) * 256.0f);
    return k < 0 ? 0 : (k > NBIN - 1 ? NBIN - 1 : k);
}

__device__ __forceinline__ void scan4(unsigned* hist, volatile unsigned* wsum, int t) {
    unsigned v[4], run = 0;
    #pragma unroll
    for (int i = 0; i < 4; ++i) { unsigned h = hist[t * 4 + i]; v[i] = run; run += h; }
    const int lane = t & 63, w = t >> 6;
    unsigned inc = run;
    #pragma unroll
    for (int off = 1; off < 64; off <<= 1) {
        unsigned nbr = __shfl_up(inc, off, 64);
        if (lane >= off) inc += nbr;
    }
    if (lane == 63) wsum[w] = inc;
    __syncthreads();
    if (t == 0) {
        unsigned r2 = 0;
        #pragma unroll
        for (int i = 0; i < 16; ++i) { unsigned h = wsum[i]; wsum[i] = r2; r2 += h; }
    }
    __syncthreads();
    unsigned base = wsum[w] + (inc - run);
    #pragma unroll
    for (int i = 0; i < 4; ++i) hist[t * 4 + i] = base + v[i];
}

__global__ __launch_bounds__(1024, 8) void k_sortdiff(
    const unsigned short* __restrict__ xp, const unsigned short* __restrict__ yp,
    unsigned short* __restrict__ diff) {
    __shared__ unsigned hist[NBIN];           // 16 KB (packed y|x)
    __shared__ unsigned short ysort[N_];      // 32 KB
    __shared__ unsigned wsum[16];
    const int t = threadIdx.x;
    const unsigned* ypd = (const unsigned*)(yp + (size_t)blockIdx.x * N_);
    const unsigned* xpd = (const unsigned*)(xp + (size_t)blockIdx.x * N_);
    unsigned*       dfd = (unsigned*)(diff + (size_t)blockIdx.x * N_);

    #pragma unroll
    for (int i = 0; i < 4; ++i) hist[t + i * 1024] = 0;
    __syncthreads();

    // ---- packed count pass: stream loads, keep ONLY atomic returns ----
    unsigned jy[8], jx[8];
    #pragma unroll
    for (int i = 0; i < 2; ++i) {
        uint4 a = *(const uint4*)(ypd + i * 4096 + t * 4);
        unsigned aws[4] = {a.x, a.y, a.z, a.w};
        #pragma unroll
        for (int q = 0; q < 4; ++q) {
            unsigned j0 = atomicAdd(&hist[binof(b2f((unsigned short)(aws[q] & 0xffff)))], 1u);
            unsigned j1 = atomicAdd(&hist[binof(b2f((unsigned short)(aws[q] >> 16)))], 1u);
            jy[4*i + q] = (j0 & 0xffffu) | (j1 << 16);
        }
    }
    #pragma unroll
    for (int i = 0; i < 2; ++i) {
        uint4 c = *(const uint4*)(xpd + i * 4096 + t * 4);
        unsigned cws[4] = {c.x, c.y, c.z, c.w};
        #pragma unroll
        for (int q = 0; q < 4; ++q) {
            unsigned i0 = atomicAdd(&hist[binof(b2f((unsigned short)(cws[q] & 0xffff)))], 0x10000u);
            unsigned i1 = atomicAdd(&hist[binof(b2f((unsigned short)(cws[q] >> 16)))], 0x10000u);
            jx[4*i + q] = (i0 >> 16) | (i1 & 0xffff0000u);
        }
    }
    __syncthreads();
    scan4(hist, wsum, t);                     // packed exclusive prefix, both fields
    __syncthreads();

    // ---- scatter y into LDS (reload y from L2, recompute bins) ----
    #pragma unroll
    for (int i = 0; i < 2; ++i) {
        uint4 a = *(const uint4*)(ypd + i * 4096 + t * 4);
        unsigned aws[4] = {a.x, a.y, a.z, a.w};
        #pragma unroll
        for (int q = 0; q < 4; ++q) {
            int k = 4*i + q;
            unsigned short e0 = (unsigned short)(aws[q] & 0xffff);
            unsigned short e1 = (unsigned short)(aws[q] >> 16);
            ysort[(hist[binof(b2f(e0))] & 0xffffu) + (jy[k] & 0xffffu)] = e0;
            ysort[(hist[binof(b2f(e1))] & 0xffffu) + (jy[k] >> 16)]     = e1;
        }
    }
    __syncthreads();

    // ---- gather transported y + diff (reload x from L2) ----
    #pragma unroll
    for (int i = 0; i < 2; ++i) {
        uint4 c = *(const uint4*)(xpd + i * 4096 + t * 4);
        unsigned cws[4] = {c.x, c.y, c.z, c.w};
        unsigned o[4];
        #pragma unroll
        for (int q = 0; q < 4; ++q) {
            int k = 4*i + q;
            float x0 = b2f((unsigned short)(cws[q] & 0xffff));
            float x1 = b2f((unsigned short)(cws[q] >> 16));
            unsigned r0 = (hist[binof(x0)] >> 16) + (jx[k] & 0xffffu);
            unsigned r1 = (hist[binof(x1)] >> 16) + (jx[k] >> 16);
            unsigned short d0 = f2b(b2f(ysort[r0]) - x0);
            unsigned short d1 = f2b(b2f(ysort[r1]) - x1);
            o[q] = (unsigned)d0 | ((unsigned)d1 << 16);
        }
        *(uint4*)(dfd + i * 4096 + t * 4) = make_uint4(o[0], o[1], o[2], o[3]);
    }
}

// ---------------------------------------------------------------------------
// Kernel 4: combine via bf16 MFMA, transpose fused into the LDS stage.
// R12: 256-ROW TILE.  Same proven per-thread body as R8/R9 (af[4] frags,
// thbT staged in two halves, direct epilogue stores), re-gridded to 1024
// threads (16 waves) x 256 rows, grid 256 = 1 block/CU = one round.  thbT
// staging traffic / 4.  Lp [64 k2][260] dwords (pair-packed, k2 50..63
// zeroed = NaN-safe K-pad; 2-way bank aliasing on frag reads = free).
// LDS 83,968 B -> 1 block/CU, 16 waves/CU.  launch_bounds(1024,4): cap 128.
// ---------------------------------------------------------------------------
__global__ __launch_bounds__(1024, 4) void k_comb(
    const float* __restrict__ x, const unsigned short* __restrict__ diff,
    const unsigned short* __restrict__ thbT, float* __restrict__ out) {
    __shared__ unsigned short ths[64 * 136];  // 17,408 B (half of thbT)
    __shared__ unsigned Lp[64 * 260];         // 66,560 B [k2][row] pair-packed
    const int tid  = threadIdx.x;             // 0..1023
    const int w    = tid >> 6;                // wave 0..15 -> rows w*16..+15
    const int lane = tid & 63;
    const int n16  = lane & 15;
    const int quad = lane >> 4;
    const int row0 = blockIdx.x * 256;

    for (int g = tid; g < 1024; g += 1024) {  // thbT rows 0..63 -> LDS
        int r = g >> 4, c = (g & 15) << 3;
        *(uint4*)(ths + r * 136 + c) = *(const uint4*)(thbT + r * KPAD + c);
    }
    for (int g = tid; g < 3640; g += 1024) Lp[50 * 260 + g] = 0;  // k2=50..63 pad
    for (int g = tid; g < 1600; g += 1024) {  // 50 p-pairs x 32 row-groups
        int p2 = g >> 5, rg = (g & 31) << 3;
        uint4 a = *(const uint4*)(diff + (size_t)(2 * p2) * BN_ + row0 + rg);
        uint4 b = *(const uint4*)(diff + (size_t)(2 * p2 + 1) * BN_ + row0 + rg);
        unsigned* dst = Lp + p2 * 260 + rg;
        dst[0] = (a.x & 0xffffu) | (b.x << 16);
        dst[1] = (a.x >> 16)     | (b.x & 0xffff0000u);
        dst[2] = (a.y & 0xffffu) | (b.y << 16);
        dst[3] = (a.y >> 16)     | (b.y & 0xffff0000u);
        dst[4] = (a.z & 0xffffu) | (b.z << 16);
        dst[5] = (a.z >> 16)     | (b.z & 0xffff0000u);
        dst[6] = (a.w & 0xffffu) | (b.w << 16);
        dst[7] = (a.w >> 16)     | (b.w & 0xffff0000u);
    }
    __syncthreads();

    // A-frags: lane row r = w*16+n16 (0..255), k = ks*32 + quad*8 + 0..7
    const int r = w * 16 + n16;
    short8 af[4];
    #pragma unroll
    for (int ks = 0; ks < 4; ++ks) {
        union { unsigned u[4]; short8 v; } tu;
        #pragma unroll
        for (int m = 0; m < 4; ++m)
            tu.u[m] = Lp[(ks * 16 + quad * 4 + m) * 260 + r];
        af[ks] = tu.v;
    }

    const float invP = 1.0f / (float)P_;
    const size_t rbase = (size_t)(row0 + w * 16 + quad * 4) * D_ + n16;

    // ---- pass 0: d 0..63 ----
    #pragma unroll
    for (int nt = 0; nt < 4; ++nt) {
        floatx4 acc = {0.f, 0.f, 0.f, 0.f};
        #pragma unroll
        for (int ks = 0; ks < 4; ++ks) {
            short8 b = *(const short8*)(ths + (nt * 16 + n16) * 136 + ks * 32 + quad * 8);
            acc = __builtin_amdgcn_mfma_f32_16x16x32_bf16(af[ks], b, acc, 0, 0, 0);
        }
        #pragma unroll
        for (int reg = 0; reg < 4; ++reg) {
            size_t o = rbase + (size_t)reg * D_ + nt * 16;
            out[o] = fmaf(acc[reg], invP, x[o]);
        }
    }
    __syncthreads();                          // all waves done with ths half0

    for (int g = tid; g < 1024; g += 1024) {  // thbT rows 64..127 -> LDS
        int r2 = g >> 4, c = (g & 15) << 3;
        *(uint4*)(ths + r2 * 136 + c) = *(const uint4*)(thbT + (size_t)(64 + r2) * KPAD + c);
    }
    __syncthreads();

    // ---- pass 1: d 64..127 ----
    #pragma unroll
    for (int nt = 0; nt < 4; ++nt) {
        floatx4 acc = {0.f, 0.f, 0.f, 0.f};
        #pragma unroll
        for (int ks = 0; ks < 4; ++ks) {
            short8 b = *(const short8*)(ths + (nt * 16 + n16) * 136 + ks * 32 + quad * 8);
            acc = __builtin_amdgcn_mfma_f32_16x16x32_bf16(af[ks], b, acc, 0, 0, 0);
        }
        #pragma unroll
        for (int reg = 0; reg < 4; ++reg) {
            size_t o = rbase + (size_t)reg * D_ + (64 + nt * 16);
            out[o] = fmaf(acc[reg], invP, x[o]);
        }
    }
}

// ---------------------------------------------------------------------------
// Workspace (bytes): thb[0, 32KB) thbT[32KB, 64KB) xp[64KB, +13.1MB)
// yp(+13.1MB) => ~26.3 MB. diff overwrites xp in place.
// ---------------------------------------------------------------------------
extern "C" void kernel_launch(void* const* d_in, const int* in_sizes, int n_in,
                              void* d_out, int out_size, void* d_ws, size_t ws_size,
                              hipStream_t stream) {
    const float* x  = (const float*)d_in[0];
    const float* y  = (const float*)d_in[1];
    const float* th = (const float*)d_in[2];
    float* out = (float*)d_out;
    char*  wsb = (char*)d_ws;

    unsigned short* thb  = (unsigned short*)wsb;
    unsigned short* thbT = (unsigned short*)(wsb + 32768);
    unsigned short* xpb  = (unsigned short*)(wsb + 65536);
    unsigned short* ypb  = xpb + PBN_;

    k_norm<<<128, 128, 0, stream>>>(th, thb, thbT);
    k_proj<<<BN_ / 256, 1024, 0, stream>>>(x, y, thb, xpb, ypb);
    k_sortdiff<<<P_ * B_, 1024, 0, stream>>>(xpb, ypb, xpb);
    k_comb<<<BN_ / 256, 1024, 0, stream>>>(x, xpb, thbT, out);
}